// Round 4
// baseline (52.521 us; speedup 1.0000x reference)
//
#include <hip/hip_runtime.h>
#include <hip/hip_bf16.h>
#include <math.h>

#define B_ROWS 4096
#define N_ROWS 8192
#define D_DIM  128
// (1/T) * log2(e) = 2 * 1.4426950408889634
#define SCALE_LOG2 2.8853900817779268f
// sqrt(SCALE_LOG2): folded into row normalization so MFMA output is already
// in log2 domain (saves 16 v_mul per tile before exp2)
#define PRESCALE 1.6986436f

#define CSPLIT 32
#define CHUNK (N_ROWS / CSPLIT)        // 256 cols per block
#define TILES_PER_CHUNK (CHUNK / 32)   // 8 column tiles
#define ROWS_PER_WAVE 64               // 2 MFMA row-tiles per wave
#define ROWS_PER_BLOCK (4 * ROWS_PER_WAVE)  // 256

typedef __bf16 bf16x8 __attribute__((ext_vector_type(8)));
typedef __bf16 bf16x2 __attribute__((ext_vector_type(2)));
typedef float  f32x16 __attribute__((ext_vector_type(16)));

#if __has_builtin(__builtin_amdgcn_exp2f)
#define EXP2F(x) __builtin_amdgcn_exp2f(x)
#else
#define EXP2F(x) exp2f(x)
#endif

// Packed fragment-major layout (16B chunk units):
//   chunk(p, kk, l) = zn[p*32 + (l&31)][ (kk*2 + (l>>5))*8 .. +8 ]   (8 bf16)
//   addr16B = p*512 + kk*64 + l
// one wave MFMA-fragment load = 64 consecutive 16B chunks = 1KB coalesced.

// ---------- K1: normalize rows of concat(z_i, z_j) -> packed bf16 ----------
__global__ __launch_bounds__(256) void k_normalize(const float* __restrict__ zi,
                                                   const float* __restrict__ zj,
                                                   __bf16* __restrict__ pack) {
    const int wid  = threadIdx.x >> 6;
    const int lane = threadIdx.x & 63;
    const int row  = blockIdx.x * 4 + wid;
    const float* src = (row < B_ROWS) ? (zi + (size_t)row * D_DIM)
                                      : (zj + (size_t)(row - B_ROWS) * D_DIM);
    float2 v = ((const float2*)src)[lane];
    float ss = v.x * v.x + v.y * v.y;
    #pragma unroll
    for (int off = 1; off < 64; off <<= 1) ss += __shfl_xor(ss, off, 64);
    float inv = PRESCALE / fmaxf(sqrtf(ss), 1e-8f);
    bf16x2 o;
    o[0] = (__bf16)(v.x * inv);
    o[1] = (__bf16)(v.y * inv);
    // elements e = 2*lane, 2*lane+1 -> kk = lane>>3, h = (lane>>2)&1, m = lane&3
    const int chunk = ((row >> 5) << 9) + ((lane >> 3) << 6) +
                      (((lane >> 2) & 1) << 5) + (row & 31);
    ((bf16x2*)pack)[chunk * 4 + (lane & 3)] = o;
}

// ---------- K2: NT-GEMM (zn . zn^T) with fused exp2 row-sum ----------
// block = 4 waves; wave w owns 64 rows (two 32-row MFMA tiles) -> each B-tile
// load feeds 16 MFMAs + 32 exp2 (2x arithmetic intensity vs 32-row waves,
// halving the L1/L2 fragment-load traffic that bounds this kernel).
// B is loaded in K=64 halves (b[4]) to cap VGPR pressure.
__global__ __launch_bounds__(256) void k_gemm_expsum(const __bf16* __restrict__ pack,
                                                     float* __restrict__ partials) {
    const int rb   = blockIdx.x;   // 0..31 row-block (256 rows)
    const int cs   = blockIdx.y;   // 0..31 column split (256 cols)
    const int wid  = threadIdx.x >> 6;
    const int lane = threadIdx.x & 63;
    const int h    = lane >> 5;    // lane half (k-group)
    const int ln   = lane & 31;

    const int row0 = rb * ROWS_PER_BLOCK + wid * ROWS_PER_WAVE;
    const bf16x8* pk = (const bf16x8*)pack;   // 16B chunk units

    // A fragments for two row tiles: coalesced panel loads
    const size_t pa = (size_t)(row0 >> 5) * 512;
    bf16x8 a0[8], a1[8];
    #pragma unroll
    for (int kk = 0; kk < 8; ++kk) {
        a0[kk] = pk[pa + kk * 64 + lane];
        a1[kk] = pk[pa + 512 + kk * 64 + lane];
    }

    float sums0[16], sums1[16];
    #pragma unroll
    for (int i = 0; i < 16; ++i) { sums0[i] = 0.0f; sums1[i] = 0.0f; }

    const int pc0 = cs * TILES_PER_CHUNK;   // first column panel index
    for (int ct = 0; ct < TILES_PER_CHUNK; ++ct) {
        const size_t pb = (size_t)(pc0 + ct) * 512;
        f32x16 acc0 = {};
        f32x16 acc1 = {};
        #pragma unroll
        for (int kh = 0; kh < 2; ++kh) {
            bf16x8 b[4];
            #pragma unroll
            for (int k2 = 0; k2 < 4; ++k2)
                b[k2] = pk[pb + (kh * 4 + k2) * 64 + lane];
            #pragma unroll
            for (int k2 = 0; k2 < 4; ++k2) {
                acc0 = __builtin_amdgcn_mfma_f32_32x32x16_bf16(a0[kh * 4 + k2], b[k2], acc0, 0, 0, 0);
                acc1 = __builtin_amdgcn_mfma_f32_32x32x16_bf16(a1[kh * 4 + k2], b[k2], acc1, 0, 0, 0);
            }
        }
        // rows pre-scaled by sqrt(2/ln2): acc is already logit*log2e.
        // logits bounded by 1/T=2 -> plain exp2 accumulation, no max tracking
        #pragma unroll
        for (int i = 0; i < 16; ++i) {
            sums0[i] += EXP2F(acc0[i]);
            sums1[i] += EXP2F(acc1[i]);
        }
    }

    // reduce each row's sum across the 32 lanes of its half (cols), then the
    // lane whose ln == reg writes that reg's row. Static indexing throughout.
    #pragma unroll
    for (int i = 0; i < 16; ++i) {
        float s0 = sums0[i];
        float s1 = sums1[i];
        #pragma unroll
        for (int off = 1; off < 32; off <<= 1) {
            s0 += __shfl_xor(s0, off, 64);
            s1 += __shfl_xor(s1, off, 64);
        }
        if (ln == i) {
            const int rloc = (i & 3) + 8 * (i >> 2) + 4 * h;  // measured C layout
            partials[(size_t)cs * N_ROWS + row0 + rloc]      = s0;
            partials[(size_t)cs * N_ROWS + row0 + 32 + rloc] = s1;
        }
    }
}

// ---------- K3: merge partials + label logit + nll -> loss ----------
// block = 4 waves, 32 rows/block (grid 256); 32 lanes per row (j = lane&31 ==
// cs index); 2 rows per wave-iteration.
__global__ __launch_bounds__(256) void k_finalize(const __bf16* __restrict__ pack,
                                                  const float* __restrict__ partials,
                                                  float* __restrict__ out) {
    const int wid  = threadIdx.x >> 6;
    const int lane = threadIdx.x & 63;
    const int j    = lane & 31;            // partial-split index
    const int sub  = lane >> 5;            // 0..1: row within pair
    const int rowbase = blockIdx.x * 32 + wid * 8;
    const bf16x8* pk = (const bf16x8*)pack;

    float accv = 0.0f;
    #pragma unroll
    for (int it = 0; it < 4; ++it) {
        const int r = rowbase + it * 2 + sub;
        const int c = (r < B_ROWS) ? r : r - B_ROWS;   // label column
        // dot over 16 groups; lanes j and j+16 duplicate group (j&15), so the
        // 32-lane reduction yields 2*PRESCALE^2*cos = 2*SCALE_LOG2*cos.
        const int g = j & 15;
        const int goff = ((g >> 1) << 6) + ((g & 1) << 5);
        bf16x8 av = pk[(size_t)(r >> 5) * 512 + goff + (r & 31)];
        bf16x8 bv = pk[(size_t)(c >> 5) * 512 + goff + (c & 31)];
        float d = 0.0f;
        #pragma unroll
        for (int e = 0; e < 8; ++e) d += (float)av[e] * (float)bv[e];
        float p = partials[(size_t)j * N_ROWS + r];
        #pragma unroll
        for (int off = 1; off < 32; off <<= 1) {
            d += __shfl_xor(d, off, 64);
            p += __shfl_xor(p, off, 64);
        }
        if (j == 0) {
            // nll = lse - logit_label = ln(row_sum) - 2*cos(r,label)
            accv += logf(p) - d * (1.0f / SCALE_LOG2);
        }
    }
    #pragma unroll
    for (int off = 1; off < 64; off <<= 1) accv += __shfl_xor(accv, off, 64);
    __shared__ float ls[4];
    if (lane == 0) ls[wid] = accv;
    __syncthreads();
    if (threadIdx.x == 0) {
        atomicAdd(out, (ls[0] + ls[1] + ls[2] + ls[3]) * (1.0f / (float)N_ROWS));
    }
}

extern "C" void kernel_launch(void* const* d_in, const int* in_sizes, int n_in,
                              void* d_out, int out_size, void* d_ws, size_t ws_size,
                              hipStream_t stream) {
    const float* zi = (const float*)d_in[0];
    const float* zj = (const float*)d_in[1];
    float* out = (float*)d_out;

    __bf16* pack     = (__bf16*)d_ws;                                      // 2 MB
    float*  partials = (float*)((char*)d_ws + (size_t)N_ROWS * D_DIM * 2); // 1 MB

    hipMemsetAsync(out, 0, sizeof(float), stream);
    k_normalize<<<dim3(N_ROWS / 4), dim3(256), 0, stream>>>(zi, zj, pack);
    k_gemm_expsum<<<dim3(N_ROWS / ROWS_PER_BLOCK, CSPLIT), dim3(256), 0, stream>>>(pack, partials);
    k_finalize<<<dim3(N_ROWS / 32), dim3(256), 0, stream>>>(pack, partials, out);
}

// Round 5
// 50.799 us; speedup vs baseline: 1.0339x; 1.0339x over previous
//
#include <hip/hip_runtime.h>
#include <hip/hip_bf16.h>
#include <math.h>

#define B_ROWS 4096
#define N_ROWS 8192
#define D_DIM  128
// (1/T) * log2(e) = 2 * 1.4426950408889634
#define SCALE_LOG2 2.8853900817779268f
// sqrt(SCALE_LOG2): folded into row normalization so MFMA output is already
// in log2 domain (saves 16 v_mul per tile before exp2)
#define PRESCALE 1.6986436f

#define CSPLIT 32
#define CHUNK (N_ROWS / CSPLIT)        // 256 cols per block
#define TILES_PER_CHUNK (CHUNK / 32)   // 8 column tiles

typedef __bf16 bf16x8 __attribute__((ext_vector_type(8)));
typedef __bf16 bf16x2 __attribute__((ext_vector_type(2)));
typedef float  f32x16 __attribute__((ext_vector_type(16)));

#if __has_builtin(__builtin_amdgcn_exp2f)
#define EXP2F(x) __builtin_amdgcn_exp2f(x)
#else
#define EXP2F(x) exp2f(x)
#endif

// Packed fragment-major layout (16B chunk units):
//   chunk(p, kk, l) = zn[p*32 + (l&31)][ (kk*2 + (l>>5))*8 .. +8 ]   (8 bf16)
//   addr16B = p*512 + kk*64 + l
// one wave MFMA-fragment load = 64 consecutive 16B chunks = 1KB coalesced.

// ---------- K1: normalize rows of concat(z_i, z_j) -> packed bf16 ----------
__global__ __launch_bounds__(256) void k_normalize(const float* __restrict__ zi,
                                                   const float* __restrict__ zj,
                                                   __bf16* __restrict__ pack) {
    const int wid  = threadIdx.x >> 6;
    const int lane = threadIdx.x & 63;
    const int row  = blockIdx.x * 4 + wid;
    const float* src = (row < B_ROWS) ? (zi + (size_t)row * D_DIM)
                                      : (zj + (size_t)(row - B_ROWS) * D_DIM);
    float2 v = ((const float2*)src)[lane];
    float ss = v.x * v.x + v.y * v.y;
    #pragma unroll
    for (int off = 1; off < 64; off <<= 1) ss += __shfl_xor(ss, off, 64);
    float inv = PRESCALE / fmaxf(sqrtf(ss), 1e-8f);
    bf16x2 o;
    o[0] = (__bf16)(v.x * inv);
    o[1] = (__bf16)(v.y * inv);
    // elements e = 2*lane, 2*lane+1 -> kk = lane>>3, h = (lane>>2)&1, m = lane&3
    const int chunk = ((row >> 5) << 9) + ((lane >> 3) << 6) +
                      (((lane >> 2) & 1) << 5) + (row & 31);
    ((bf16x2*)pack)[chunk * 4 + (lane & 3)] = o;
}

// ---------- K2: NT-GEMM (zn . zn^T) with fused exp2 row-sum ----------
// block = 4 waves; wave w owns rows [rb*128 + w*32, +32); 32 rows/wave keeps
// register state small. Tile loop is 2x-unrolled with alternating register
// B-buffers: tile ct+1's 8 coalesced 1KB loads are issued BEFORE tile ct's
// MFMA+exp2 consume the current buffer, so the ~300cy L2 latency hides under
// ~200cy of compute (counted vmcnt, compiler-inserted). ILP instead of TLP.
__global__ __launch_bounds__(256) void k_gemm_expsum(const __bf16* __restrict__ pack,
                                                     float* __restrict__ partials) {
    const int rb   = blockIdx.x;   // 0..63 row-block
    const int cs   = blockIdx.y;   // 0..31 column split
    const int wid  = threadIdx.x >> 6;
    const int lane = threadIdx.x & 63;
    const int h    = lane >> 5;    // lane half (k-group)
    const int ln   = lane & 31;

    const int row0 = rb * 128 + wid * 32;
    const bf16x8* pk = (const bf16x8*)pack;   // 16B chunk units

    // A fragments: coalesced panel loads (one 32-row panel, K=128)
    const size_t pa = (size_t)(row0 >> 5) * 512;
    bf16x8 a[8];
    #pragma unroll
    for (int kk = 0; kk < 8; ++kk)
        a[kk] = pk[pa + kk * 64 + lane];

    float sums[16];
    #pragma unroll
    for (int i = 0; i < 16; ++i) sums[i] = 0.0f;

    const int pc0 = cs * TILES_PER_CHUNK;   // first column panel index
    bf16x8 b0[8], b1[8];
    #pragma unroll
    for (int kk = 0; kk < 8; ++kk)
        b0[kk] = pk[(size_t)pc0 * 512 + kk * 64 + lane];

    #pragma unroll
    for (int ct = 0; ct < TILES_PER_CHUNK; ct += 2) {
        // prefetch tile ct+1 into b1 (loads in flight during b0's compute)
        #pragma unroll
        for (int kk = 0; kk < 8; ++kk)
            b1[kk] = pk[(size_t)(pc0 + ct + 1) * 512 + kk * 64 + lane];
        {
            f32x16 acc = {};
            #pragma unroll
            for (int kk = 0; kk < 8; ++kk)
                acc = __builtin_amdgcn_mfma_f32_32x32x16_bf16(a[kk], b0[kk], acc, 0, 0, 0);
            #pragma unroll
            for (int i = 0; i < 16; ++i) sums[i] += EXP2F(acc[i]);
        }
        // prefetch tile ct+2 into b0
        if (ct + 2 < TILES_PER_CHUNK) {
            #pragma unroll
            for (int kk = 0; kk < 8; ++kk)
                b0[kk] = pk[(size_t)(pc0 + ct + 2) * 512 + kk * 64 + lane];
        }
        {
            f32x16 acc = {};
            #pragma unroll
            for (int kk = 0; kk < 8; ++kk)
                acc = __builtin_amdgcn_mfma_f32_32x32x16_bf16(a[kk], b1[kk], acc, 0, 0, 0);
            #pragma unroll
            for (int i = 0; i < 16; ++i) sums[i] += EXP2F(acc[i]);
        }
    }

    // reduce each row's sum across the 32 lanes of its half (cols), then the
    // lane whose ln == reg writes that reg's row. Static indexing throughout.
    #pragma unroll
    for (int i = 0; i < 16; ++i) {
        float s = sums[i];
        #pragma unroll
        for (int off = 1; off < 32; off <<= 1) s += __shfl_xor(s, off, 64);
        if (ln == i) {
            const int rloc = (i & 3) + 8 * (i >> 2) + 4 * h;  // measured C layout
            partials[(size_t)cs * N_ROWS + row0 + rloc] = s;
        }
    }
}

// ---------- K3: merge partials + label logit + nll -> loss ----------
// block = 4 waves, 32 rows/block (grid 256); 32 lanes per row (j = lane&31 ==
// cs index); 2 rows per wave-iteration.
__global__ __launch_bounds__(256) void k_finalize(const __bf16* __restrict__ pack,
                                                  const float* __restrict__ partials,
                                                  float* __restrict__ out) {
    const int wid  = threadIdx.x >> 6;
    const int lane = threadIdx.x & 63;
    const int j    = lane & 31;            // partial-split index
    const int sub  = lane >> 5;            // 0..1: row within pair
    const int rowbase = blockIdx.x * 32 + wid * 8;
    const bf16x8* pk = (const bf16x8*)pack;

    float accv = 0.0f;
    #pragma unroll
    for (int it = 0; it < 4; ++it) {
        const int r = rowbase + it * 2 + sub;
        const int c = (r < B_ROWS) ? r : r - B_ROWS;   // label column
        // dot over 16 groups; lanes j and j+16 duplicate group (j&15), so the
        // 32-lane reduction yields 2*PRESCALE^2*cos = 2*SCALE_LOG2*cos.
        const int g = j & 15;
        const int goff = ((g >> 1) << 6) + ((g & 1) << 5);
        bf16x8 av = pk[(size_t)(r >> 5) * 512 + goff + (r & 31)];
        bf16x8 bv = pk[(size_t)(c >> 5) * 512 + goff + (c & 31)];
        float d = 0.0f;
        #pragma unroll
        for (int e = 0; e < 8; ++e) d += (float)av[e] * (float)bv[e];
        float p = partials[(size_t)j * N_ROWS + r];
        #pragma unroll
        for (int off = 1; off < 32; off <<= 1) {
            d += __shfl_xor(d, off, 64);
            p += __shfl_xor(p, off, 64);
        }
        if (j == 0) {
            // nll = lse - logit_label = ln(row_sum) - 2*cos(r,label)
            accv += logf(p) - d * (1.0f / SCALE_LOG2);
        }
    }
    #pragma unroll
    for (int off = 1; off < 64; off <<= 1) accv += __shfl_xor(accv, off, 64);
    __shared__ float ls[4];
    if (lane == 0) ls[wid] = accv;
    __syncthreads();
    if (threadIdx.x == 0) {
        atomicAdd(out, (ls[0] + ls[1] + ls[2] + ls[3]) * (1.0f / (float)N_ROWS));
    }
}

extern "C" void kernel_launch(void* const* d_in, const int* in_sizes, int n_in,
                              void* d_out, int out_size, void* d_ws, size_t ws_size,
                              hipStream_t stream) {
    const float* zi = (const float*)d_in[0];
    const float* zj = (const float*)d_in[1];
    float* out = (float*)d_out;

    __bf16* pack     = (__bf16*)d_ws;                                      // 2 MB
    float*  partials = (float*)((char*)d_ws + (size_t)N_ROWS * D_DIM * 2); // 1 MB

    hipMemsetAsync(out, 0, sizeof(float), stream);
    k_normalize<<<dim3(N_ROWS / 4), dim3(256), 0, stream>>>(zi, zj, pack);
    k_gemm_expsum<<<dim3(64, CSPLIT), dim3(256), 0, stream>>>(pack, partials);
    k_finalize<<<dim3(N_ROWS / 32), dim3(256), 0, stream>>>(pack, partials, out);
}

// Round 6
// 48.763 us; speedup vs baseline: 1.0771x; 1.0418x over previous
//
#include <hip/hip_runtime.h>
#include <hip/hip_bf16.h>
#include <math.h>

#define B_ROWS 4096
#define N_ROWS 8192
#define D_DIM  128
// (1/T) * log2(e) = 2 * 1.4426950408889634
#define SCALE_LOG2 2.8853900817779268f
// sqrt(SCALE_LOG2): folded into row normalization so MFMA output is already
// in log2 domain (saves 16 v_mul per tile before exp2)
#define PRESCALE 1.6986436f

#define CSPLIT 32
#define CHUNK (N_ROWS / CSPLIT)        // 256 cols per block
#define TILES_PER_CHUNK (CHUNK / 32)   // 8 column tiles

typedef __bf16 bf16x8 __attribute__((ext_vector_type(8)));
typedef __bf16 bf16x2 __attribute__((ext_vector_type(2)));
typedef float  f32x16 __attribute__((ext_vector_type(16)));

#if __has_builtin(__builtin_amdgcn_exp2f)
#define EXP2F(x) __builtin_amdgcn_exp2f(x)
#else
#define EXP2F(x) exp2f(x)
#endif

// Packed fragment-major layout (16B chunk units):
//   chunk(p, kk, l) = zn[p*32 + (l&31)][ (kk*2 + (l>>5))*8 .. +8 ]   (8 bf16)
//   addr16B = p*512 + kk*64 + l
// one wave MFMA-fragment load = 64 consecutive 16B chunks = 1KB coalesced.

// ---------- K1: normalize rows of concat(z_i, z_j) -> packed bf16 ----------
__global__ __launch_bounds__(256) void k_normalize(const float* __restrict__ zi,
                                                   const float* __restrict__ zj,
                                                   __bf16* __restrict__ pack) {
    const int wid  = threadIdx.x >> 6;
    const int lane = threadIdx.x & 63;
    const int row  = blockIdx.x * 4 + wid;
    const float* src = (row < B_ROWS) ? (zi + (size_t)row * D_DIM)
                                      : (zj + (size_t)(row - B_ROWS) * D_DIM);
    float2 v = ((const float2*)src)[lane];
    float ss = v.x * v.x + v.y * v.y;
    #pragma unroll
    for (int off = 1; off < 64; off <<= 1) ss += __shfl_xor(ss, off, 64);
    float inv = PRESCALE / fmaxf(sqrtf(ss), 1e-8f);
    bf16x2 o;
    o[0] = (__bf16)(v.x * inv);
    o[1] = (__bf16)(v.y * inv);
    // elements e = 2*lane, 2*lane+1 -> kk = lane>>3, h = (lane>>2)&1, m = lane&3
    const int chunk = ((row >> 5) << 9) + ((lane >> 3) << 6) +
                      (((lane >> 2) & 1) << 5) + (row & 31);
    ((bf16x2*)pack)[chunk * 4 + (lane & 3)] = o;
}

// ---------- K2: NT-GEMM (zn . zn^T) with fused exp2 row-sum ----------
// block = 4 waves; wave w owns rows [rb*128 + w*32, +32). B panels (8KB per
// 32-col tile) are staged into LDS once per BLOCK and ds_read by all 4 waves:
// cuts the per-wave private B re-load (512MB of L1 gather traffic, the
// measured bottleneck: ~30cyc/1KB wave-load in the TA) down to 2 staging
// loads/wave/tile + stride-1 ds_read_b128 at ~12cyc/KB on the LDS pipe.
// Double-buffered, issue-early/write-late (T14): next tile's global loads are
// in flight during the current tile's MFMA+exp2.
__global__ __launch_bounds__(256) void k_gemm_expsum(const __bf16* __restrict__ pack,
                                                     float* __restrict__ partials) {
    const int rb   = blockIdx.x;   // 0..63 row-block
    const int cs   = blockIdx.y;   // 0..31 column split
    const int wid  = threadIdx.x >> 6;
    const int lane = threadIdx.x & 63;
    const int h    = lane >> 5;    // lane half (k-group)
    const int ln   = lane & 31;
    const int t    = threadIdx.x;

    __shared__ bf16x8 ldsB[1024];  // 2 x 8KB double buffer (16B chunk units)

    const int row0 = rb * 128 + wid * 32;
    const bf16x8* pk = (const bf16x8*)pack;   // 16B chunk units

    // A fragments: coalesced panel loads (one 32-row panel, K=128)
    const size_t pa = (size_t)(row0 >> 5) * 512;
    bf16x8 a[8];
    #pragma unroll
    for (int kk = 0; kk < 8; ++kk)
        a[kk] = pk[pa + kk * 64 + lane];

    float sums[16];
    #pragma unroll
    for (int i = 0; i < 16; ++i) sums[i] = 0.0f;

    const int pc0 = cs * TILES_PER_CHUNK;   // first column panel index
    // preload tile 0 into staging regs (2 x 16B per thread covers 8KB/block)
    bf16x8 st0 = pk[(size_t)pc0 * 512 + t];
    bf16x8 st1 = pk[(size_t)pc0 * 512 + 256 + t];

    for (int ct = 0; ct < TILES_PER_CHUNK; ++ct) {
        const int buf = (ct & 1) << 9;       // 0 / 512 chunk offset
        __syncthreads();                     // prior reads of this buf complete
        ldsB[buf + t]       = st0;
        ldsB[buf + 256 + t] = st1;
        if (ct + 1 < TILES_PER_CHUNK) {      // issue next tile's loads EARLY
            st0 = pk[(size_t)(pc0 + ct + 1) * 512 + t];
            st1 = pk[(size_t)(pc0 + ct + 1) * 512 + 256 + t];
        }
        __syncthreads();                     // staged panel visible to block

        f32x16 acc = {};
        #pragma unroll
        for (int kk = 0; kk < 8; ++kk) {
            bf16x8 b = ldsB[buf + kk * 64 + lane];   // stride-1 ds_read_b128
            acc = __builtin_amdgcn_mfma_f32_32x32x16_bf16(a[kk], b, acc, 0, 0, 0);
        }
        // rows pre-scaled by sqrt(2/ln2): acc is already logit*log2e.
        // logits bounded by 1/T=2 -> plain exp2 accumulation, no max tracking
        #pragma unroll
        for (int i = 0; i < 16; ++i)
            sums[i] += EXP2F(acc[i]);
    }

    // reduce each row's sum across the 32 lanes of its half (cols), then the
    // lane whose ln == reg writes that reg's row. Static indexing throughout.
    #pragma unroll
    for (int i = 0; i < 16; ++i) {
        float s = sums[i];
        #pragma unroll
        for (int off = 1; off < 32; off <<= 1) s += __shfl_xor(s, off, 64);
        if (ln == i) {
            const int rloc = (i & 3) + 8 * (i >> 2) + 4 * h;  // measured C layout
            partials[(size_t)cs * N_ROWS + row0 + rloc] = s;
        }
    }
}

// ---------- K3: merge partials + label logit + nll -> loss ----------
// block = 4 waves, 32 rows/block (grid 256); 32 lanes per row (j = lane&31 ==
// cs index); 2 rows per wave-iteration.
__global__ __launch_bounds__(256) void k_finalize(const __bf16* __restrict__ pack,
                                                  const float* __restrict__ partials,
                                                  float* __restrict__ out) {
    const int wid  = threadIdx.x >> 6;
    const int lane = threadIdx.x & 63;
    const int j    = lane & 31;            // partial-split index
    const int sub  = lane >> 5;            // 0..1: row within pair
    const int rowbase = blockIdx.x * 32 + wid * 8;
    const bf16x8* pk = (const bf16x8*)pack;

    float accv = 0.0f;
    #pragma unroll
    for (int it = 0; it < 4; ++it) {
        const int r = rowbase + it * 2 + sub;
        const int c = (r < B_ROWS) ? r : r - B_ROWS;   // label column
        // dot over 16 groups; lanes j and j+16 duplicate group (j&15), so the
        // 32-lane reduction yields 2*PRESCALE^2*cos = 2*SCALE_LOG2*cos.
        const int g = j & 15;
        const int goff = ((g >> 1) << 6) + ((g & 1) << 5);
        bf16x8 av = pk[(size_t)(r >> 5) * 512 + goff + (r & 31)];
        bf16x8 bv = pk[(size_t)(c >> 5) * 512 + goff + (c & 31)];
        float d = 0.0f;
        #pragma unroll
        for (int e = 0; e < 8; ++e) d += (float)av[e] * (float)bv[e];
        float p = partials[(size_t)j * N_ROWS + r];
        #pragma unroll
        for (int off = 1; off < 32; off <<= 1) {
            d += __shfl_xor(d, off, 64);
            p += __shfl_xor(p, off, 64);
        }
        if (j == 0) {
            // nll = lse - logit_label = ln(row_sum) - 2*cos(r,label)
            accv += logf(p) - d * (1.0f / SCALE_LOG2);
        }
    }
    #pragma unroll
    for (int off = 1; off < 64; off <<= 1) accv += __shfl_xor(accv, off, 64);
    __shared__ float ls[4];
    if (lane == 0) ls[wid] = accv;
    __syncthreads();
    if (threadIdx.x == 0) {
        atomicAdd(out, (ls[0] + ls[1] + ls[2] + ls[3]) * (1.0f / (float)N_ROWS));
    }
}

extern "C" void kernel_launch(void* const* d_in, const int* in_sizes, int n_in,
                              void* d_out, int out_size, void* d_ws, size_t ws_size,
                              hipStream_t stream) {
    const float* zi = (const float*)d_in[0];
    const float* zj = (const float*)d_in[1];
    float* out = (float*)d_out;

    __bf16* pack     = (__bf16*)d_ws;                                      // 2 MB
    float*  partials = (float*)((char*)d_ws + (size_t)N_ROWS * D_DIM * 2); // 1 MB

    hipMemsetAsync(out, 0, sizeof(float), stream);
    k_normalize<<<dim3(N_ROWS / 4), dim3(256), 0, stream>>>(zi, zj, pack);
    k_gemm_expsum<<<dim3(64, CSPLIT), dim3(256), 0, stream>>>(pack, partials);
    k_finalize<<<dim3(N_ROWS / 32), dim3(256), 0, stream>>>(pack, partials, out);
}